// Round 8
// baseline (314.067 us; speedup 1.0000x reference)
//
#include <hip/hip_runtime.h>

// ---------------------------------------------------------------------------
// ConstraintViolationLoss: build x; sparse Ax via deterministic counting-sort
// with WAVE-PRIVATE LDS write-combining FIFOs (zero barriers, zero cross-wave
// contention, 3-slot load/gather pipeline); LDS bucket accumulation; fused
// violation reduction to 4 scalars: [penalty, mean_viol, max_viol, n_viol].
//
// History: r1/r4: fp32 global atomics are memory-side regardless of scope
// (500MB RMW). r2/r5: scattered stores -> 0.9-1.0GB write-allocate traffic.
// r6/r7: block-shared FIFO write-combining fixes bytes (WRITE 70MB ~= logical)
// but 16 barriers/chunk + unprefetched x-gather cap scatter at 2.2TB/s.
// r8: wave-private FIFOs (no barriers) + pipelined gather + parallel scan +
// uint4 accum loads.
// ---------------------------------------------------------------------------

#define BSHIFT 14
#define BROWS  (1 << BSHIFT)     // 16384 rows/bucket
#define NBUCK_MAX 32
#define STRIP 2048               // edges per wave (scan granularity)
#define NIT   (STRIP / 256)      // 8 iters: 64 lanes x 4 edges
#define SBUF  48                 // FIFO depth per bucket per wave
#define STHRESH 32               // flush threshold
#define SPLIT 16                 // accumulate blocks per bucket

typedef int   iv4 __attribute__((ext_vector_type(4)));
typedef float fv4 __attribute__((ext_vector_type(4)));

__device__ inline unsigned bf16bits(float v) {
    unsigned f = __float_as_uint(v);
    return (f + 0x7FFFu + ((f >> 16) & 1u)) >> 16;   // RNE
}

// ---------------- K1: fused edge histogram (per-strip) + build-x ------------

__global__ __launch_bounds__(256) void k_build_hist(
    const float* __restrict__ prob_bin, const int* __restrict__ idx_bin, int NB, int gBin,
    const float* __restrict__ logits, const float* __restrict__ offs,
    const int* __restrict__ idx_small, int NS, int gSml,
    const float* __restrict__ pred, const int* __restrict__ idx_large, int NL, int gLrg,
    const int* __restrict__ vt, const float* __restrict__ vf, int NV, int gCnt,
    const int* __restrict__ rows, int* __restrict__ counts,
    int nstrips, int gHist, int E, int nbuck,
    float* __restrict__ x, float* __restrict__ acc)
{
    int blk = blockIdx.x, tid = threadIdx.x;
    if (blk == 0 && tid < 4) reinterpret_cast<unsigned*>(acc)[tid] = 0u;

    if (blk < gHist) {                        // ---- histogram: 4 strips/block
        __shared__ int h[4][NBUCK_MAX];
        int wid = tid >> 6, lane = tid & 63;
        int strip = blk * 4 + wid;
        if (strip >= nstrips) return;
        if (lane < NBUCK_MAX) h[wid][lane] = 0;
        int e4max = E >> 2;
        int b4 = strip * (STRIP / 4);
#pragma unroll
        for (int k = 0; k < NIT; ++k) {
            int i4 = b4 + k * 64 + lane;
            if (i4 < e4max) {
                iv4 r = reinterpret_cast<const iv4*>(rows)[i4];
                atomicAdd(&h[wid][r.x >> BSHIFT], 1);
                atomicAdd(&h[wid][r.y >> BSHIFT], 1);
                atomicAdd(&h[wid][r.z >> BSHIFT], 1);
                atomicAdd(&h[wid][r.w >> BSHIFT], 1);
            }
        }
        if (strip == 0 && lane < (E & 3))
            atomicAdd(&h[wid][rows[(E & ~3) + lane] >> BSHIFT], 1);
        if (lane < nbuck) counts[(size_t)lane * nstrips + strip] = h[wid][lane];
        return;
    }
    blk -= gHist;
    if (blk < gBin) {                         // ---- binary scatter
        int i = blk * 256 + tid;
        if (i < NB) x[idx_bin[i]] = prob_bin[i];
        return;
    }
    blk -= gBin;
    if (blk < gSml) {                         // ---- small-int softmax E[]
        int i = blk * 256 + tid;
        if (i < NS) {
            const fv4* lp = reinterpret_cast<const fv4*>(logits + (size_t)i * 16);
            fv4 v0 = lp[0], v1 = lp[1], v2 = lp[2], v3 = lp[3];
            float l[16] = {v0.x, v0.y, v0.z, v0.w, v1.x, v1.y, v1.z, v1.w,
                           v2.x, v2.y, v2.z, v2.w, v3.x, v3.y, v3.z, v3.w};
            float m = l[0];
#pragma unroll
            for (int j = 1; j < 16; ++j) m = fmaxf(m, l[j]);
            float s = 0.f, ws = 0.f;
#pragma unroll
            for (int j = 0; j < 16; ++j) {
                float e = expf(l[j] - m);
                s += e;
                ws += e * (float)j;
            }
            x[idx_small[i]] = ws / s + offs[i];
        }
        return;
    }
    blk -= gSml;
    if (blk < gLrg) {                         // ---- large-int scatter
        int i = blk * 256 + tid;
        if (i < NL) x[idx_large[i]] = pred[i];
        return;
    }
    blk -= gLrg;
    {                                         // ---- continuous override
        int v = blk * 256 + tid;
        if (v < NV && vt[v] == 0) x[v] = vf[(size_t)v * 16 + 8];
    }
}

// ---------- K2: per-bucket scan over strips (two-tier, 1024 threads) --------

__global__ __launch_bounds__(1024) void k_scan(const int* __restrict__ counts,
                                               int* __restrict__ off,
                                               int* __restrict__ total, int nstrips) {
    int b = blockIdx.x;
    __shared__ int wtot[16];
    __shared__ int wbase[16];
    int tid = threadIdx.x, w = tid >> 6, lane = tid & 63;
    int seg = (nstrips + 15) >> 4;
    int lo = w * seg;
    int hi = lo + seg; if (hi > nstrips) hi = nstrips;
    const int* cb = counts + (size_t)b * nstrips;
    int* ob = off + (size_t)b * nstrips;
    int carry = 0;
    for (int i0 = lo; i0 < hi; i0 += 64) {
        int i = i0 + lane;
        int v = (i < hi) ? cb[i] : 0;
        int orig = v;
#pragma unroll
        for (int o = 1; o < 64; o <<= 1) {
            int t = __shfl_up(v, o, 64);
            if (lane >= o) v += t;
        }
        if (i < hi) ob[i] = carry + v - orig;
        carry += __shfl(v, 63, 64);
    }
    if (lane == 0) wtot[w] = carry;
    __syncthreads();
    if (tid == 0) {
        int s = 0;
        for (int k = 0; k < 16; ++k) { wbase[k] = s; s += wtot[k]; }
        total[b] = s;
    }
    __syncthreads();
    int add = wbase[w];
    if (add)
        for (int i = lo + lane; i < hi; i += 64) ob[i] += add;
}

// ------- K3: bucket bases (padded to x4) + zero-fill gap records ------------

__global__ void k_bases(const int* __restrict__ total, int* __restrict__ base,
                        unsigned* __restrict__ recs, int nbuck) {
    __shared__ int sb[NBUCK_MAX + 1];
    __shared__ int st[NBUCK_MAX];
    int tid = threadIdx.x;
    if (tid == 0) {
        int s = 0;
        for (int b = 0; b < nbuck; ++b) {
            sb[b] = s;
            st[b] = total[b];
            s += (total[b] + 3) & ~3;          // pad each bucket to multiple of 4
        }
        sb[nbuck] = s;
    }
    __syncthreads();
    if (tid <= nbuck) base[tid] = sb[tid];
    if (tid < nbuck) {
        int g0 = sb[tid] + st[tid], g1 = sb[tid] + ((st[tid] + 3) & ~3);
        for (int g = g0; g < g1; ++g) recs[g] = 0u;   // pack(loc=0, +0.0f)
    }
}

// ---- K4: scatter, wave-private FIFOs, zero barriers, pipelined gather ------

__global__ __launch_bounds__(256) void k_scatter4(const int* __restrict__ rows,
                                                  const int* __restrict__ cols,
                                                  const float* __restrict__ ef,
                                                  const float* __restrict__ x,
                                                  const int* __restrict__ off,
                                                  const int* __restrict__ base,
                                                  unsigned* __restrict__ recs,
                                                  int nstrips, int E, int nbuck) {
    __shared__ unsigned bufr[4][NBUCK_MAX][SBUF];   // 24KB, wave-private
    __shared__ int      fillm[4][NBUCK_MAX];        // 512B, wave-private

    int tid = threadIdx.x, wid = tid >> 6, lane = tid & 63;
    int strip = blockIdx.x * 4 + wid;
    if (strip >= nstrips) return;                   // wave-uniform exit

    unsigned (*buf)[SBUF] = bufr[wid];
    int* fl = fillm[wid];
    if (lane < NBUCK_MAX) fl[lane] = 0;

    // lane b owns bucket b's cursor
    int cbase_r = 0, done_r = 0;
    if (lane < nbuck) cbase_r = base[lane] + off[(size_t)lane * nstrips + strip];

    int e4max = E >> 2;
    int b4 = strip * (STRIP / 4);

    auto PUSH1 = [&](int rr, float prod) {
        int b = rr >> BSHIFT;
        unsigned rec = ((unsigned)(rr & (BROWS - 1)) << 16) | bf16bits(prod);
        int pos = atomicAdd(&fl[b], 1);
        if (pos < SBUF) buf[b][pos] = rec;
        else recs[__shfl(cbase_r + done_r, b) + pos] = rec;   // rare spill
    };
    auto FLUSH = [&](int thresh) {
        int myf = (lane < nbuck) ? fl[lane] : 0;
        unsigned long long m = __ballot(myf >= thresh);
        while (m) {
            int b = __ffsll((long long)m) - 1; m &= m - 1;
            int fb = __shfl(myf, b);
            int cur = __shfl(cbase_r + done_r, b);
            int n = fb < SBUF ? fb : SBUF;
            if (lane < n) recs[cur + lane] = buf[b][lane];
            if (lane == b) { done_r += fb; fl[b] = 0; }
        }
    };

    // 3-slot pipeline: streams 2 deep, gathers 1 deep
    iv4 rs[3], cs[3]; fv4 fs[3]; bool vs[3]; fv4 gs[2];
#define LOADS(it, s)                                                          \
    {   int i4 = b4 + (it) * 64 + lane;                                       \
        vs[s] = i4 < e4max;                                                   \
        if (vs[s]) {                                                          \
            rs[s] = __builtin_nontemporal_load(reinterpret_cast<const iv4*>(rows) + i4); \
            cs[s] = __builtin_nontemporal_load(reinterpret_cast<const iv4*>(cols) + i4); \
            fs[s] = __builtin_nontemporal_load(reinterpret_cast<const fv4*>(ef) + i4);   \
        } }
#define GATH(s, g)                                                            \
    if (vs[s]) {                                                              \
        gs[g].x = x[cs[s].x]; gs[g].y = x[cs[s].y];                           \
        gs[g].z = x[cs[s].z]; gs[g].w = x[cs[s].w];                           \
    }

    LOADS(0, 0)
    LOADS(1, 1)
    GATH(0, 0)
#pragma unroll
    for (int it = 0; it < NIT; ++it) {
        int s = it % 3, g = it & 1;
        if (it + 2 < NIT) LOADS(it + 2, (it + 2) % 3)
        if (it + 1 < NIT) GATH((it + 1) % 3, g ^ 1)
        if (vs[s]) {
            PUSH1(rs[s].x, fs[s].x * gs[g].x);
            PUSH1(rs[s].y, fs[s].y * gs[g].y);
            PUSH1(rs[s].z, fs[s].z * gs[g].z);
            PUSH1(rs[s].w, fs[s].w * gs[g].w);
        }
        FLUSH(STHRESH);
    }
#undef LOADS
#undef GATH
    if (strip == 0 && lane < (E & 3)) {               // scalar tail
        int e = (E & ~3) + lane;
        PUSH1(rows[e], ef[e] * x[cols[e]]);
    }
    FLUSH(1);                                         // drain
}

// -------- K5: LDS bucket accumulate (uint4 loads); store partials -----------

typedef unsigned uv4 __attribute__((ext_vector_type(4)));

__global__ __launch_bounds__(256) void k_accum(const unsigned* __restrict__ recs,
                                               const int* __restrict__ base,
                                               float* __restrict__ partial) {
    __shared__ float tile[BROWS];   // 64KB
    int tid = threadIdx.x;
    int b = blockIdx.x / SPLIT, s = blockIdx.x % SPLIT;
    fv4 z = {0.f, 0.f, 0.f, 0.f};
    for (int i = tid; i < BROWS / 4; i += 256) reinterpret_cast<fv4*>(tile)[i] = z;
    __syncthreads();
    int lo = base[b], hi = base[b + 1];               // both multiples of 4
    int len = hi - lo;
    int per = ((len + SPLIT - 1) / SPLIT + 3) & ~3;
    int s0 = lo + s * per;
    int s1 = s0 + per; if (s1 > hi) s1 = hi;
    for (int i = s0 + (tid << 2); i + 3 < s1; i += 1024) {
        uv4 r = __builtin_nontemporal_load(reinterpret_cast<const uv4*>(recs + i));
        atomicAdd(&tile[(r.x >> 16) & (BROWS - 1)], __uint_as_float((r.x & 0xFFFFu) << 16));
        atomicAdd(&tile[(r.y >> 16) & (BROWS - 1)], __uint_as_float((r.y & 0xFFFFu) << 16));
        atomicAdd(&tile[(r.z >> 16) & (BROWS - 1)], __uint_as_float((r.z & 0xFFFFu) << 16));
        atomicAdd(&tile[(r.w >> 16) & (BROWS - 1)], __uint_as_float((r.w & 0xFFFFu) << 16));
    }
    __syncthreads();
    float* out = partial + ((size_t)blockIdx.x << BSHIFT);
    for (int i = tid; i < BROWS / 4; i += 256)
        __builtin_nontemporal_store(reinterpret_cast<const fv4*>(tile)[i],
                                    reinterpret_cast<fv4*>(out) + i);
}

// ------- K6: fold partials + bias + relu + reduce + ticketed finalize -------

__global__ __launch_bounds__(256) void k_reduce_fin(const float* __restrict__ partial,
                                                    const float* __restrict__ cf,
                                                    float* __restrict__ acc,
                                                    float* __restrict__ out,
                                                    int ncon, int nblocks) {
    float lsum = 0.f, lmax = 0.f;
    unsigned lcnt = 0;
    int stride = gridDim.x * blockDim.x;
    for (int c = blockIdx.x * blockDim.x + threadIdx.x; c < ncon; c += stride) {
        int b = c >> BSHIFT, i = c & (BROWS - 1);
        const float* p = partial + (((size_t)b * SPLIT) << BSHIFT) + i;
        float v = 0.f;
#pragma unroll
        for (int s = 0; s < SPLIT; ++s)
            v += __builtin_nontemporal_load(p + ((size_t)s << BSHIFT));
        v -= cf[(size_t)c * 8 + 1];
        v = v > 0.f ? v : 0.f;
        lsum += v;
        lmax = fmaxf(lmax, v);
        lcnt += (v > 1e-6f) ? 1u : 0u;
    }
#pragma unroll
    for (int o = 32; o > 0; o >>= 1) {
        lsum += __shfl_down(lsum, o);
        lmax = fmaxf(lmax, __shfl_down(lmax, o));
        lcnt += __shfl_down(lcnt, o);
    }
    __shared__ float ssum[4];
    __shared__ float smax[4];
    __shared__ unsigned scnt[4];
    int lane = threadIdx.x & 63, wid = threadIdx.x >> 6;
    if (lane == 0) { ssum[wid] = lsum; smax[wid] = lmax; scnt[wid] = lcnt; }
    __syncthreads();
    if (threadIdx.x == 0) {
        float bs = 0.f, bm = 0.f;
        unsigned bc = 0;
        for (int w = 0; w < 4; ++w) { bs += ssum[w]; bm = fmaxf(bm, smax[w]); bc += scnt[w]; }
        atomicAdd(&acc[0], bs);
        atomicMax(reinterpret_cast<unsigned*>(acc) + 1, __float_as_uint(bm));
        atomicAdd(reinterpret_cast<unsigned*>(acc) + 2, bc);
        __threadfence();
        unsigned t = atomicAdd(reinterpret_cast<unsigned*>(acc) + 3, 1u);
        if (t == (unsigned)(nblocks - 1)) {
            float sum   = atomicAdd(&acc[0], 0.f);
            unsigned mb = atomicMax(reinterpret_cast<unsigned*>(acc) + 1, 0u);
            unsigned ct = atomicAdd(reinterpret_cast<unsigned*>(acc) + 2, 0u);
            float mean = sum / (float)ncon;
            float mx = __uint_as_float(mb);
            out[0] = mean + 0.1f * mx;
            out[1] = mean;
            out[2] = mx;
            out[3] = (float)ct;
        }
    }
}

// ------------------- fallback: direct device-scope atomics ------------------

__global__ void k_scatter_f(const float* __restrict__ src, const int* __restrict__ idx,
                            float* __restrict__ x, int n) {
    int i = blockIdx.x * blockDim.x + threadIdx.x;
    if (i < n) x[idx[i]] = src[i];
}

__global__ void k_small_int_f(const float* __restrict__ logits, const float* __restrict__ offs,
                              const int* __restrict__ idx, float* __restrict__ x, int n) {
    int i = blockIdx.x * blockDim.x + threadIdx.x;
    if (i >= n) return;
    const fv4* lp = reinterpret_cast<const fv4*>(logits + (size_t)i * 16);
    fv4 v0 = lp[0], v1 = lp[1], v2 = lp[2], v3 = lp[3];
    float l[16] = {v0.x, v0.y, v0.z, v0.w, v1.x, v1.y, v1.z, v1.w,
                   v2.x, v2.y, v2.z, v2.w, v3.x, v3.y, v3.z, v3.w};
    float m = l[0];
#pragma unroll
    for (int j = 1; j < 16; ++j) m = fmaxf(m, l[j]);
    float s = 0.f, ws = 0.f;
#pragma unroll
    for (int j = 0; j < 16; ++j) {
        float e = expf(l[j] - m);
        s += e;
        ws += e * (float)j;
    }
    x[idx[i]] = ws / s + offs[i];
}

__global__ void k_continuous_f(const int* __restrict__ vt, const float* __restrict__ vf,
                               float* __restrict__ x, int n) {
    int v = blockIdx.x * blockDim.x + threadIdx.x;
    if (v < n && vt[v] == 0) x[v] = vf[(size_t)v * 16 + 8];
}

__global__ void k_edges(const float* __restrict__ ef, const int* __restrict__ rows,
                        const int* __restrict__ cols, const float* __restrict__ x,
                        float* __restrict__ Ax, int e4, int E) {
    int stride = gridDim.x * blockDim.x;
    int gid = blockIdx.x * blockDim.x + threadIdx.x;
    for (int i = gid; i < e4; i += stride) {
        fv4 f = reinterpret_cast<const fv4*>(ef)[i];
        iv4 r = reinterpret_cast<const iv4*>(rows)[i];
        iv4 c = reinterpret_cast<const iv4*>(cols)[i];
        atomicAdd(&Ax[r.x], f.x * x[c.x]);
        atomicAdd(&Ax[r.y], f.y * x[c.y]);
        atomicAdd(&Ax[r.z], f.z * x[c.z]);
        atomicAdd(&Ax[r.w], f.w * x[c.w]);
    }
    for (int e = e4 * 4 + gid; e < E; e += stride)
        atomicAdd(&Ax[rows[e]], ef[e] * x[cols[e]]);
}

__global__ void k_reduce_ax(const float* __restrict__ Ax, const float* __restrict__ cf,
                            float* __restrict__ acc, int ncon) {
    float lsum = 0.f, lmax = 0.f;
    unsigned lcnt = 0;
    int stride = gridDim.x * blockDim.x;
    for (int c = blockIdx.x * blockDim.x + threadIdx.x; c < ncon; c += stride) {
        float v = Ax[c] - cf[(size_t)c * 8 + 1];
        v = v > 0.f ? v : 0.f;
        lsum += v;
        lmax = fmaxf(lmax, v);
        lcnt += (v > 1e-6f) ? 1u : 0u;
    }
#pragma unroll
    for (int o = 32; o > 0; o >>= 1) {
        lsum += __shfl_down(lsum, o);
        lmax = fmaxf(lmax, __shfl_down(lmax, o));
        lcnt += __shfl_down(lcnt, o);
    }
    __shared__ float ssum[4];
    __shared__ float smax[4];
    __shared__ unsigned scnt[4];
    int lane = threadIdx.x & 63, wid = threadIdx.x >> 6;
    if (lane == 0) { ssum[wid] = lsum; smax[wid] = lmax; scnt[wid] = lcnt; }
    __syncthreads();
    if (threadIdx.x == 0) {
        float bs = 0.f, bm = 0.f;
        unsigned bc = 0;
        for (int w = 0; w < 4; ++w) { bs += ssum[w]; bm = fmaxf(bm, smax[w]); bc += scnt[w]; }
        atomicAdd(&acc[0], bs);
        atomicMax(reinterpret_cast<unsigned*>(acc) + 1, __float_as_uint(bm));
        atomicAdd(reinterpret_cast<unsigned*>(acc) + 2, bc);
    }
}

__global__ void k_final(const float* __restrict__ acc, float* __restrict__ out, int ncon) {
    if (blockIdx.x == 0 && threadIdx.x == 0) {
        float sum = acc[0];
        float mx = __uint_as_float(reinterpret_cast<const unsigned*>(acc)[1]);
        unsigned cnt = reinterpret_cast<const unsigned*>(acc)[2];
        float mean = sum / (float)ncon;
        out[0] = mean + 0.1f * mx;
        out[1] = mean;
        out[2] = mx;
        out[3] = (float)cnt;
    }
}

// ------------------------------ launcher -----------------------------------

extern "C" void kernel_launch(void* const* d_in, const int* in_sizes, int n_in,
                              void* d_out, int out_size, void* d_ws, size_t ws_size,
                              hipStream_t stream) {
    const float* prob_bin     = (const float*)d_in[0];
    const float* logits_small = (const float*)d_in[1];
    const float* offs_small   = (const float*)d_in[2];
    const float* pred_large   = (const float*)d_in[3];
    const float* edge_feat    = (const float*)d_in[4];
    const float* cons_feat    = (const float*)d_in[5];
    const float* var_feat     = (const float*)d_in[6];
    const int*   idx_bin      = (const int*)d_in[7];
    const int*   idx_small    = (const int*)d_in[8];
    const int*   idx_large    = (const int*)d_in[9];
    const int*   var_types    = (const int*)d_in[10];
    const int*   edge_indices = (const int*)d_in[11];

    const int NB    = in_sizes[0];
    const int NS    = in_sizes[2];
    const int NL    = in_sizes[3];
    const int E     = in_sizes[4];
    const int NCON  = in_sizes[5] / 8;
    const int NVARS = in_sizes[10];

    const int* rows = edge_indices;
    const int* cols = edge_indices + E;

    const int nbuck   = (NCON + BROWS - 1) >> BSHIFT;
    const int nstrips = (E + STRIP - 1) / STRIP;

    // ws layout (256B-aligned regions)
    char* w = (char*)d_ws;
    size_t o = 0;
    auto take = [&](size_t bytes) -> char* {
        char* p = w + o;
        o = (o + bytes + 255) & ~(size_t)255;
        return p;
    };
    float*    x       = (float*)take((size_t)NVARS * 4);
    unsigned* recs    = (unsigned*)take((size_t)(E + 4 * NBUCK_MAX) * 4);
    float*    partial = (float*)take((size_t)nbuck * SPLIT * BROWS * 4);
    int*      counts  = (int*)take((size_t)nbuck * nstrips * 4);
    int*      off     = (int*)take((size_t)nbuck * nstrips * 4);
    int*      base    = (int*)take((size_t)(nbuck + 1) * 4);
    int*      total   = (int*)take((size_t)nbuck * 4);
    float*    acc     = (float*)take(16);

    bool sorted_path = (o <= ws_size) && (nbuck <= NBUCK_MAX);

    const int B = 256;

    if (sorted_path) {
        const int gHist = (nstrips + 3) / 4;
        const int gBin  = (NB + B - 1) / B;
        const int gSml  = (NS + B - 1) / B;
        const int gLrg  = (NL + B - 1) / B;
        const int gCnt  = (NVARS + B - 1) / B;
        const int grid1 = gHist + gBin + gSml + gLrg + gCnt;

        k_build_hist<<<grid1, B, 0, stream>>>(
            prob_bin, idx_bin, NB, gBin,
            logits_small, offs_small, idx_small, NS, gSml,
            pred_large, idx_large, NL, gLrg,
            var_types, var_feat, NVARS, gCnt,
            rows, counts, nstrips, gHist, E, nbuck, x, acc);
        k_scan<<<nbuck, 1024, 0, stream>>>(counts, off, total, nstrips);
        k_bases<<<1, 64, 0, stream>>>(total, base, recs, nbuck);
        k_scatter4<<<(nstrips + 3) / 4, B, 0, stream>>>(rows, cols, edge_feat, x, off, base,
                                                        recs, nstrips, E, nbuck);
        k_accum<<<nbuck * SPLIT, B, 0, stream>>>(recs, base, partial);
        const int rblocks = 1024;
        k_reduce_fin<<<rblocks, B, 0, stream>>>(partial, cons_feat, acc, (float*)d_out,
                                                NCON, rblocks);
    } else {
        float* accf = (float*)((char*)d_ws + (size_t)NVARS * 4);
        float* Ax   = accf + 4;
        (void)hipMemsetAsync(accf, 0, (size_t)(4 + NCON) * sizeof(float), stream);
        k_scatter_f<<<(NB + B - 1) / B, B, 0, stream>>>(prob_bin, idx_bin, x, NB);
        k_small_int_f<<<(NS + B - 1) / B, B, 0, stream>>>(logits_small, offs_small, idx_small, x, NS);
        k_scatter_f<<<(NL + B - 1) / B, B, 0, stream>>>(pred_large, idx_large, x, NL);
        k_continuous_f<<<(NVARS + B - 1) / B, B, 0, stream>>>(var_types, var_feat, x, NVARS);
        k_edges<<<2048, B, 0, stream>>>(edge_feat, rows, cols, x, Ax, E / 4, E);
        k_reduce_ax<<<1024, B, 0, stream>>>(Ax, cons_feat, accf, NCON);
        k_final<<<1, 64, 0, stream>>>(accf, (float*)d_out, NCON);
    }
}